// Round 2
// baseline (602.986 us; speedup 1.0000x reference)
//
#include <hip/hip_runtime.h>
#include <hip/hip_bf16.h>

// Workspace float slots:
// 0: cls_loss  1: noobj  2: S0(count obj)  3: S1_p0  4: S2_p0  5: S1_p1  6: S2_p1
// 7: reg_p0    8: reg_p1
// int slots (after NQ floats): [0] = max obj index, [1] = block ticket
#define NQ   9
#define TILE 256

__global__ __launch_bounds__(256) void yolo_fused_kernel(
    const float* __restrict__ pred,
    const float* __restrict__ tbox,
    const float* __restrict__ tcls,
    const int*   __restrict__ obj,
    float* __restrict__ ws_f,
    int*   __restrict__ ws_i,
    float* __restrict__ out,
    int M, float invN, int nblocks)
{
    // pred tile staged verbatim (stride 30 floats/cell). 30720 B -> 5 blocks/CU.
    __shared__ float sp[TILE * 30];

    const int t  = threadIdx.x;
    const int c0 = blockIdx.x * TILE;
    const int nc = min(TILE, M - c0);

    // ---- stage pred tile: identity float4 copy, fully coalesced ----
    if (nc == TILE) {
        const float4* pv = reinterpret_cast<const float4*>(pred + (size_t)c0 * 30);
        float4* spv = reinterpret_cast<float4*>(sp);
#pragma unroll
        for (int j = 0; j < 8; ++j) {          // 1920 float4 total
            int i = j * 256 + t;
            if (i < 1920) spv[i] = pv[i];
        }
    } else {
        for (int e = t; e < nc * 30; e += 256) sp[e] = pred[(size_t)c0 * 30 + e];
    }
    __syncthreads();

    float acc[NQ];
#pragma unroll
    for (int q = 0; q < NQ; ++q) acc[q] = 0.f;
    int imax = -1;

    // ---- cls phase: coalesced float4 over tcls, pred ch10-29 from LDS ----
    if (nc == TILE) {
        const float4* cv = reinterpret_cast<const float4*>(tcls + (size_t)c0 * 20);
#pragma unroll
        for (int j = 0; j < 5; ++j) {          // 1280 float4 total
            int i = j * 256 + t;
            float4 v = cv[i];
            int cell = i / 5;                  // 5 float4 per cell
            int ch   = (i - cell * 5) * 4;
            const float* s = sp + cell * 30 + 10 + ch;
            float d0 = s[0] - v.x, d1 = s[1] - v.y;
            float d2 = s[2] - v.z, d3 = s[3] - v.w;
            acc[0] += d0 * d0 + d1 * d1 + d2 * d2 + d3 * d3;
        }
    } else {
        for (int e = t; e < nc * 20; e += 256) {
            int cell = e / 20, ch = e - cell * 20;
            float d = sp[cell * 30 + 10 + ch] - tcls[(size_t)c0 * 20 + e];
            acc[0] += d * d;
        }
    }

    // ---- per-cell phase: thread t owns cell c0+t ----
    if (t < nc) {
        const int cell = c0 + t;
        const float* s = sp + t * 30;
        const float p0c = s[4];
        const bool o = (obj[cell] != 0);
        if (!o) {
            acc[1] += p0c * p0c;               // L_NOOBJ * 2 == 1.0
        } else {
            float4 tb = reinterpret_cast<const float4*>(tbox)[cell];
            acc[2] += 1.f;
            acc[3] += p0c;
            acc[4] += p0c * p0c;
            const float p1c = s[9];
            acc[5] += p1c;
            acc[6] += p1c * p1c;
            const float st2 = sqrtf(tb.z), st3 = sqrtf(tb.w);
            {
                float dx = s[0] - tb.x, dy = s[1] - tb.y;
                float dw = sqrtf(s[2]) - st2, dh = sqrtf(s[3]) - st3;
                acc[7] += dx * dx + dy * dy + dw * dw + dh * dh;
            }
            {
                float dx = s[5] - tb.x, dy = s[6] - tb.y;
                float dw = sqrtf(s[7]) - st2, dh = sqrtf(s[8]) - st3;
                acc[8] += dx * dx + dy * dy + dw * dw + dh * dh;
            }
            imax = cell;
        }
    }

    // ---- wave (64-lane) shuffle reduction ----
#pragma unroll
    for (int off = 32; off > 0; off >>= 1) {
#pragma unroll
        for (int q = 0; q < NQ; ++q) acc[q] += __shfl_down(acc[q], off, 64);
        imax = max(imax, __shfl_down(imax, off, 64));
    }

    __shared__ float sred[4][NQ];
    __shared__ int   sidx[4];
    const int lane = t & 63;
    const int wid  = t >> 6;
    if (lane == 0) {
#pragma unroll
        for (int q = 0; q < NQ; ++q) sred[wid][q] = acc[q];
        sidx[wid] = imax;
    }
    __syncthreads();

    if (t == 0) {
        float tot[NQ];
        int   mx = sidx[0];
#pragma unroll
        for (int q = 0; q < NQ; ++q) tot[q] = sred[0][q];
        for (int w = 1; w < 4; ++w) {
#pragma unroll
            for (int q = 0; q < NQ; ++q) tot[q] += sred[w][q];
            mx = max(mx, sidx[w]);
        }
#pragma unroll
        for (int q = 0; q < NQ; ++q) atomicAdd(&ws_f[q], tot[q]);
        atomicMax(&ws_i[0], mx);
        __threadfence();
        const int ticket = atomicAdd(&ws_i[1], 1);

        if (ticket == nblocks - 1) {
            // ---- last block: finalize. All ws reads via atomics (XCD-safe). ----
            float sums[NQ];
#pragma unroll
            for (int q = 0; q < NQ; ++q) sums[q] = atomicAdd(&ws_f[q], 0.f);
            const int idx = atomicMax(&ws_i[0], -1);

            const float* p  = pred + (size_t)idx * 30;
            const float* tb = tbox + (size_t)idx * 4;

            float b0[4], b1[4], bt[4];
            {
                float cx = p[0] / 14.f, cy = p[1] / 14.f;
                b0[0] = cx - 0.5f * p[2]; b0[1] = cy - 0.5f * p[3];
                b0[2] = cx + 0.5f * p[2]; b0[3] = cy + 0.5f * p[3];
            }
            {
                float cx = p[5] / 14.f, cy = p[6] / 14.f;
                b1[0] = cx - 0.5f * p[7]; b1[1] = cy - 0.5f * p[8];
                b1[2] = cx + 0.5f * p[7]; b1[3] = cy + 0.5f * p[8];
            }
            {
                float cx = tb[0] / 14.f, cy = tb[1] / 14.f;
                bt[0] = cx - 0.5f * tb[2]; bt[1] = cy - 0.5f * tb[3];
                bt[2] = cx + 0.5f * tb[2]; bt[3] = cy + 0.5f * tb[3];
            }
            auto iou = [](const float* a, const float* b) {
                float ltx = fmaxf(a[0], b[0]), lty = fmaxf(a[1], b[1]);
                float rbx = fminf(a[2], b[2]), rby = fminf(a[3], b[3]);
                float w = fmaxf(rbx - ltx, 0.f), h = fmaxf(rby - lty, 0.f);
                float inter = w * h;
                float a1 = (a[2] - a[0]) * (a[3] - a[1]);
                float a2 = (b[2] - b[0]) * (b[3] - b[1]);
                return inter / (a1 + a2 - inter);
            };
            float iou0 = iou(b0, bt), iou1 = iou(b1, bt);
            bool  m = iou0 > iou1;
            float c = m ? iou0 : iou1;

            float S0  = sums[2];
            float S1  = m ? sums[3] : sums[5];
            float S2  = m ? sums[4] : sums[6];
            float reg = m ? sums[7] : sums[8];

            float reg_loss   = 5.f * reg;                       // L_COORD
            float containing = S2 - 2.f * c * S1 + c * c * S0;  // sum obj*(conf-c)^2
            float noobj      = sums[1];
            float cls        = sums[0];
            float total      = cls + noobj + reg_loss + containing;

            out[0] = total * invN;
            out[1] = reg_loss * invN;
            out[2] = containing * invN;
            out[3] = noobj * invN;
            out[4] = cls * invN;
        }
    }
}

extern "C" void kernel_launch(void* const* d_in, const int* in_sizes, int n_in,
                              void* d_out, int out_size, void* d_ws, size_t ws_size,
                              hipStream_t stream) {
    const float* pred = (const float*)d_in[0];
    const float* tbox = (const float*)d_in[1];
    const float* tcls = (const float*)d_in[2];
    const int*   obj  = (const int*)d_in[3];
    float* out = (float*)d_out;

    const int M = in_sizes[3];                  // BATCH * S * S
    const int N = in_sizes[0] / (14 * 14 * 30); // BATCH

    float* ws_f = (float*)d_ws;
    int*   ws_i = (int*)d_ws + NQ;

    // harness poisons d_ws to 0xAA before every launch -> zero sums+idx+ticket
    hipMemsetAsync(d_ws, 0, (NQ + 2) * sizeof(float), stream);

    const int threads = 256;
    const int nblocks = (M + TILE - 1) / TILE;
    yolo_fused_kernel<<<nblocks, threads, 0, stream>>>(
        pred, tbox, tcls, obj, ws_f, ws_i, out, M, 1.f / (float)N, nblocks);
}

// Round 3
// 205.967 us; speedup vs baseline: 2.9276x; 2.9276x over previous
//
#include <hip/hip_runtime.h>
#include <hip/hip_bf16.h>

// ws layout: NBLK rows of ROW floats each:
//   [0]=cls  [1]=noobj  [2]=S0  [3]=S1_p0  [4]=S2_p0  [5]=S1_p1  [6]=S2_p1
//   [7]=reg_p0  [8]=reg_p1  [9]=imax (int bitcast)  [10..11] pad
#define NQ   9
#define ROW  12
#define TILE 256

__global__ __launch_bounds__(256) void yolo_partial_kernel(
    const float* __restrict__ pred,
    const float* __restrict__ tbox,
    const float* __restrict__ tcls,
    const int*   __restrict__ obj,
    float* __restrict__ partial,     // [gridDim.x * ROW]
    int M)
{
    __shared__ float sp[TILE * 30];  // 30720 B
    const int t = threadIdx.x;
    const int ntiles = (M + TILE - 1) / TILE;

    float acc[NQ];
#pragma unroll
    for (int q = 0; q < NQ; ++q) acc[q] = 0.f;
    int imax = -1;

    for (int tile = blockIdx.x; tile < ntiles; tile += gridDim.x) {
        const int c0 = tile * TILE;
        const int nc = min(TILE, M - c0);

        __syncthreads();   // protect sp from previous iteration's readers

        // ---- stage pred tile: identity float4 copy, fully coalesced ----
        if (nc == TILE) {
            const float4* pv = reinterpret_cast<const float4*>(pred + (size_t)c0 * 30);
            float4* spv = reinterpret_cast<float4*>(sp);
#pragma unroll
            for (int j = 0; j < 8; ++j) {        // 1920 float4 total
                int i = j * 256 + t;
                if (i < 1920) spv[i] = pv[i];
            }
        } else {
            for (int e = t; e < nc * 30; e += 256) sp[e] = pred[(size_t)c0 * 30 + e];
        }
        __syncthreads();

        // ---- cls phase: coalesced float4 over tcls, pred ch10-29 from LDS ----
        if (nc == TILE) {
            const float4* cv = reinterpret_cast<const float4*>(tcls + (size_t)c0 * 20);
#pragma unroll
            for (int j = 0; j < 5; ++j) {        // 1280 float4 total
                int i = j * 256 + t;
                float4 v = cv[i];
                int cell = i / 5;                // 5 float4 per cell
                int ch   = (i - cell * 5) * 4;
                const float* s = sp + cell * 30 + 10 + ch;
                float d0 = s[0] - v.x, d1 = s[1] - v.y;
                float d2 = s[2] - v.z, d3 = s[3] - v.w;
                acc[0] += d0 * d0 + d1 * d1 + d2 * d2 + d3 * d3;
            }
        } else {
            for (int e = t; e < nc * 20; e += 256) {
                int cell = e / 20, ch = e - cell * 20;
                float d = sp[cell * 30 + 10 + ch] - tcls[(size_t)c0 * 20 + e];
                acc[0] += d * d;
            }
        }

        // ---- per-cell phase: thread t owns cell c0+t ----
        if (t < nc) {
            const int cell = c0 + t;
            const float* s = sp + t * 30;
            const float p0c = s[4];
            const bool o = (obj[cell] != 0);
            if (!o) {
                acc[1] += p0c * p0c;             // L_NOOBJ * 2 == 1.0
            } else {
                float4 tb = reinterpret_cast<const float4*>(tbox)[cell];
                acc[2] += 1.f;
                acc[3] += p0c;
                acc[4] += p0c * p0c;
                const float p1c = s[9];
                acc[5] += p1c;
                acc[6] += p1c * p1c;
                const float st2 = sqrtf(tb.z), st3 = sqrtf(tb.w);
                {
                    float dx = s[0] - tb.x, dy = s[1] - tb.y;
                    float dw = sqrtf(s[2]) - st2, dh = sqrtf(s[3]) - st3;
                    acc[7] += dx * dx + dy * dy + dw * dw + dh * dh;
                }
                {
                    float dx = s[5] - tb.x, dy = s[6] - tb.y;
                    float dw = sqrtf(s[7]) - st2, dh = sqrtf(s[8]) - st3;
                    acc[8] += dx * dx + dy * dy + dw * dw + dh * dh;
                }
                imax = cell;
            }
        }
    }

    // ---- wave (64-lane) shuffle reduction ----
#pragma unroll
    for (int off = 32; off > 0; off >>= 1) {
#pragma unroll
        for (int q = 0; q < NQ; ++q) acc[q] += __shfl_down(acc[q], off, 64);
        imax = max(imax, __shfl_down(imax, off, 64));
    }

    __shared__ float sred[4][NQ];
    __shared__ int   sidx[4];
    const int lane = t & 63;
    const int wid  = t >> 6;
    if (lane == 0) {
#pragma unroll
        for (int q = 0; q < NQ; ++q) sred[wid][q] = acc[q];
        sidx[wid] = imax;
    }
    __syncthreads();

    if (t == 0) {
        float tot[NQ];
        int   mx = sidx[0];
#pragma unroll
        for (int q = 0; q < NQ; ++q) tot[q] = sred[0][q];
        for (int w = 1; w < 4; ++w) {
#pragma unroll
            for (int q = 0; q < NQ; ++q) tot[q] += sred[w][q];
            mx = max(mx, sidx[w]);
        }
        float* row = partial + (size_t)blockIdx.x * ROW;
#pragma unroll
        for (int q = 0; q < NQ; ++q) row[q] = tot[q];
        reinterpret_cast<int*>(row)[NQ] = mx;
    }
}

__global__ __launch_bounds__(256) void yolo_final_kernel(
    const float* __restrict__ pred,
    const float* __restrict__ tbox,
    const float* __restrict__ partial,
    float* __restrict__ out,
    int nrows, float invN)
{
    const int t = threadIdx.x;
    float acc[NQ];
#pragma unroll
    for (int q = 0; q < NQ; ++q) acc[q] = 0.f;
    int imax = -1;

    for (int r = t; r < nrows; r += 256) {
        const float* row = partial + (size_t)r * ROW;
#pragma unroll
        for (int q = 0; q < NQ; ++q) acc[q] += row[q];
        imax = max(imax, reinterpret_cast<const int*>(row)[NQ]);
    }

#pragma unroll
    for (int off = 32; off > 0; off >>= 1) {
#pragma unroll
        for (int q = 0; q < NQ; ++q) acc[q] += __shfl_down(acc[q], off, 64);
        imax = max(imax, __shfl_down(imax, off, 64));
    }

    __shared__ float sred[4][NQ];
    __shared__ int   sidx[4];
    const int lane = t & 63;
    const int wid  = t >> 6;
    if (lane == 0) {
#pragma unroll
        for (int q = 0; q < NQ; ++q) sred[wid][q] = acc[q];
        sidx[wid] = imax;
    }
    __syncthreads();

    if (t == 0) {
        float sums[NQ];
        int idx = sidx[0];
#pragma unroll
        for (int q = 0; q < NQ; ++q) sums[q] = sred[0][q];
        for (int w = 1; w < 4; ++w) {
#pragma unroll
            for (int q = 0; q < NQ; ++q) sums[q] += sred[w][q];
            idx = max(idx, sidx[w]);
        }

        const float* p  = pred + (size_t)idx * 30;
        const float* tb = tbox + (size_t)idx * 4;

        float b0[4], b1[4], bt[4];
        {
            float cx = p[0] / 14.f, cy = p[1] / 14.f;
            b0[0] = cx - 0.5f * p[2]; b0[1] = cy - 0.5f * p[3];
            b0[2] = cx + 0.5f * p[2]; b0[3] = cy + 0.5f * p[3];
        }
        {
            float cx = p[5] / 14.f, cy = p[6] / 14.f;
            b1[0] = cx - 0.5f * p[7]; b1[1] = cy - 0.5f * p[8];
            b1[2] = cx + 0.5f * p[7]; b1[3] = cy + 0.5f * p[8];
        }
        {
            float cx = tb[0] / 14.f, cy = tb[1] / 14.f;
            bt[0] = cx - 0.5f * tb[2]; bt[1] = cy - 0.5f * tb[3];
            bt[2] = cx + 0.5f * tb[2]; bt[3] = cy + 0.5f * tb[3];
        }
        auto iou = [](const float* a, const float* b) {
            float ltx = fmaxf(a[0], b[0]), lty = fmaxf(a[1], b[1]);
            float rbx = fminf(a[2], b[2]), rby = fminf(a[3], b[3]);
            float w = fmaxf(rbx - ltx, 0.f), h = fmaxf(rby - lty, 0.f);
            float inter = w * h;
            float a1 = (a[2] - a[0]) * (a[3] - a[1]);
            float a2 = (b[2] - b[0]) * (b[3] - b[1]);
            return inter / (a1 + a2 - inter);
        };
        float iou0 = iou(b0, bt), iou1 = iou(b1, bt);
        bool  m = iou0 > iou1;
        float c = m ? iou0 : iou1;

        float S0  = sums[2];
        float S1  = m ? sums[3] : sums[5];
        float S2  = m ? sums[4] : sums[6];
        float reg = m ? sums[7] : sums[8];

        float reg_loss   = 5.f * reg;                       // L_COORD
        float containing = S2 - 2.f * c * S1 + c * c * S0;  // sum obj*(conf-c)^2
        float noobj      = sums[1];
        float cls        = sums[0];
        float total      = cls + noobj + reg_loss + containing;

        out[0] = total * invN;
        out[1] = reg_loss * invN;
        out[2] = containing * invN;
        out[3] = noobj * invN;
        out[4] = cls * invN;
    }
}

extern "C" void kernel_launch(void* const* d_in, const int* in_sizes, int n_in,
                              void* d_out, int out_size, void* d_ws, size_t ws_size,
                              hipStream_t stream) {
    const float* pred = (const float*)d_in[0];
    const float* tbox = (const float*)d_in[1];
    const float* tcls = (const float*)d_in[2];
    const int*   obj  = (const int*)d_in[3];
    float* out = (float*)d_out;

    const int M = in_sizes[3];                  // BATCH * S * S
    const int N = in_sizes[0] / (14 * 14 * 30); // BATCH

    // one private partial row per block; no atomics, no memset needed
    int nblk = 1024;
    const int max_rows = (int)(ws_size / (ROW * sizeof(float)));
    if (nblk > max_rows) nblk = max_rows;
    if (nblk < 1) nblk = 1;

    float* partial = (float*)d_ws;

    yolo_partial_kernel<<<nblk, 256, 0, stream>>>(pred, tbox, tcls, obj, partial, M);
    yolo_final_kernel<<<1, 256, 0, stream>>>(pred, tbox, partial, out, nblk, 1.f / (float)N);
}